// Round 1
// 439.298 us; speedup vs baseline: 1.0230x; 1.0230x over previous
//
#include <hip/hip_runtime.h>

#define NB 2048
#define MB 2048
#define SPLITS 4
#define MSP (MB / SPLITS)  // 512

typedef __attribute__((ext_vector_type(8))) short short8;
typedef __attribute__((ext_vector_type(4))) float floatx4;

__device__ __forceinline__ unsigned short f2bf(float f) {
    union { float f; unsigned int u; } v; v.f = f;
    unsigned int r = (v.u + 0x7FFFu + ((v.u >> 16) & 1u)) >> 16;
    return (unsigned short)r;
}

// XOR-swizzled LDS layout: 64 elems/row, 16B chunks swizzled by row low bits.
__device__ __forceinline__ int swz(int row, int k) {
    return (row << 6) + ((((k >> 3) ^ (row & 7))) << 3) + (k & 7);
}
// Variant for transposed-V (row = c*8+i pattern in staging).
__device__ __forceinline__ int vswz(int row, int k) {
    return (row << 6) + ((((k >> 3) ^ (row & 7) ^ ((row >> 3) & 7))) << 3) + (k & 7);
}

// async global -> LDS, 16B per lane (m97 pattern: linear LDS dest, per-lane global src)
__device__ __forceinline__ void gload16(const unsigned short* g, short* l) {
    __builtin_amdgcn_global_load_lds(
        (const __attribute__((address_space(1))) void*)g,
        (__attribute__((address_space(3))) void*)l, 16, 0, 0);
}

// ---------------------------------------------------------------------------
// prep: fused  cvt(x), cvt(x1), transpose_cvt(W_qv), (W_k), (W_out)
// blocks: [0,1024) cvt x | [1024,2048) cvt x1 | [2048,2176) Wqv | [2176,2240) Wk
//         | [2240,2304) Wout
// ---------------------------------------------------------------------------
__launch_bounds__(256)
__global__ void prep(const float* __restrict__ x, const float* __restrict__ x1,
                     const float* __restrict__ Wqv, const float* __restrict__ Wk,
                     const float* __restrict__ Wout,
                     unsigned short* __restrict__ xb, unsigned short* __restrict__ x1b,
                     unsigned short* __restrict__ Wqvt, unsigned short* __restrict__ Wkt,
                     unsigned short* __restrict__ Woutt) {
    __shared__ float t[64][65];
    const int bid = blockIdx.x, tid = threadIdx.x;
    if (bid < 2048) {
        const float* in = bid < 1024 ? x : x1;
        unsigned short* out = bid < 1024 ? xb : x1b;
        size_t off = ((size_t)(bid & 1023) * 256 + tid) * 8;
        float4 d0 = *(const float4*)(in + off);
        float4 d1 = *(const float4*)(in + off + 4);
        uint4 o;
        o.x = (unsigned int)f2bf(d0.x) | ((unsigned int)f2bf(d0.y) << 16);
        o.y = (unsigned int)f2bf(d0.z) | ((unsigned int)f2bf(d0.w) << 16);
        o.z = (unsigned int)f2bf(d1.x) | ((unsigned int)f2bf(d1.y) << 16);
        o.w = (unsigned int)f2bf(d1.z) | ((unsigned int)f2bf(d1.w) << 16);
        *(uint4*)(out + off) = o;
        return;
    }
    int tb = bid - 2048;
    const float* W; unsigned short* Wt; int N;
    if (tb < 128)      { W = Wqv;  Wt = Wqvt;  N = 1024; }
    else if (tb < 192) { tb -= 128; W = Wk;   Wt = Wkt;   N = 512; }
    else               { tb -= 192; W = Wout; Wt = Woutt; N = 512; }
    const int k0 = (tb & 7) * 64, n0 = (tb >> 3) * 64;
#pragma unroll
    for (int p = 0; p < 4; p++) {
        int idx = p * 256 + tid;
        int kr = idx >> 4, c4 = (idx & 15) << 2;
        float4 d = *(const float4*)(W + (size_t)(k0 + kr) * N + n0 + c4);
        t[kr][c4 + 0] = d.x; t[kr][c4 + 1] = d.y; t[kr][c4 + 2] = d.z; t[kr][c4 + 3] = d.w;
    }
    __syncthreads();
#pragma unroll
    for (int p = 0; p < 4; p++) {
        int idx = p * 256 + tid;
        int nr = idx >> 4, k4 = (idx & 15) << 2;
        uint2 o;
        o.x = (unsigned int)f2bf(t[k4 + 0][nr]) | ((unsigned int)f2bf(t[k4 + 1][nr]) << 16);
        o.y = (unsigned int)f2bf(t[k4 + 2][nr]) | ((unsigned int)f2bf(t[k4 + 3][nr]) << 16);
        *(uint2*)(Wt + (size_t)(n0 + nr) * 512 + k0 + k4) = o;
    }
}

// ---------------------------------------------------------------------------
// 128x128-tile bf16 GEMM (m97 structure): A [M][512], Bt [N][512], C = A@Bt^T.
// 4 waves in 2x2, each owns a 64x64 quadrant (acc 4x4 of 16x16 frags).
// Staging via global_load_lds width=16, linear LDS, 2 barriers per K-step.
// ---------------------------------------------------------------------------
template <int OUT_BF16>
__device__ __forceinline__ void gemm128_body(const unsigned short* __restrict__ A,
                                             const unsigned short* __restrict__ Bt,
                                             const float* __restrict__ bias,
                                             void* __restrict__ Cp, int Nc, int m0, int n0,
                                             short* Al, short* Bl) {
    const int tid = threadIdx.x;
    const int w = tid >> 6, lane = tid & 63;
    const int quad = lane >> 4, c16 = lane & 15;
    const int wr = (w >> 1) * 64, wc = (w & 1) * 64;

    floatx4 acc[4][4];
#pragma unroll
    for (int i = 0; i < 4; i++)
#pragma unroll
        for (int j = 0; j < 4; j++) acc[i][j] = floatx4{0.f, 0.f, 0.f, 0.f};

    const unsigned short* Ap = A + (size_t)m0 * 512;
    const unsigned short* Bp = Bt + (size_t)n0 * 512;

    for (int kk = 0; kk < 512; kk += 64) {
        // stage 128x64 A-tile + 128x64 B-tile: 8 chunks/row of 16B, 4 per thread each
#pragma unroll
        for (int p = 0; p < 4; p++) {
            int idx = p * 256 + tid;
            int row = idx >> 3, c8 = (idx & 7) << 3;
            gload16(Ap + (size_t)row * 512 + kk + c8, Al + idx * 8);
            gload16(Bp + (size_t)row * 512 + kk + c8, Bl + idx * 8);
        }
        __syncthreads();   // compiler drains vmcnt(0) before barrier
#pragma unroll
        for (int kc = 0; kc < 2; kc++) {
            short8 af[4], bf[4];
#pragma unroll
            for (int mt = 0; mt < 4; mt++)
                af[mt] = *(const short8*)&Al[(wr + mt * 16 + c16) * 64 + kc * 32 + quad * 8];
#pragma unroll
            for (int nt = 0; nt < 4; nt++)
                bf[nt] = *(const short8*)&Bl[(wc + nt * 16 + c16) * 64 + kc * 32 + quad * 8];
#pragma unroll
            for (int mt = 0; mt < 4; mt++)
#pragma unroll
                for (int nt = 0; nt < 4; nt++)
                    acc[mt][nt] = __builtin_amdgcn_mfma_f32_16x16x32_bf16(af[mt], bf[nt], acc[mt][nt], 0, 0, 0);
        }
        __syncthreads();   // all waves done reading before next overwrite
    }
#pragma unroll
    for (int mt = 0; mt < 4; mt++)
#pragma unroll
        for (int nt = 0; nt < 4; nt++)
#pragma unroll
            for (int r = 0; r < 4; r++) {
                int row = m0 + wr + mt * 16 + quad * 4 + r;
                int col = n0 + wc + nt * 16 + c16;
                float v = acc[mt][nt][r];
                if (OUT_BF16) {
                    ((unsigned short*)Cp)[(size_t)row * Nc + col] = f2bf(v);
                } else {
                    ((float*)Cp)[(size_t)row * Nc + col] = v + bias[col];
                }
            }
}

// Fused qv + k projection: blocks [0,256) -> qv (Nc=1024, 32x8 tiles),
// [256,384) -> k (Nc=512, 32x4 tiles).
__launch_bounds__(256)
__global__ void gemm_qvk(const unsigned short* __restrict__ xb, const unsigned short* __restrict__ x1b,
                         const unsigned short* __restrict__ Wqvt, const unsigned short* __restrict__ Wkt,
                         unsigned short* __restrict__ qvbf, unsigned short* __restrict__ kbf) {
    __shared__ short Al[128 * 64];
    __shared__ short Bl[128 * 64];
    int bid = blockIdx.x;
    if (bid < 256) {
        gemm128_body<1>(xb, Wqvt, nullptr, qvbf, 1024, (bid & 31) * 128, (bid >> 5) * 128, Al, Bl);
    } else {
        bid -= 256;
        gemm128_body<1>(x1b, Wkt, nullptr, kbf, 512, (bid & 31) * 128, (bid >> 5) * 128, Al, Bl);
    }
}

__launch_bounds__(256)
__global__ void gemm_out(const unsigned short* __restrict__ A, const unsigned short* __restrict__ Bt,
                         const float* __restrict__ bias, float* __restrict__ C) {
    __shared__ short Al[128 * 64];
    __shared__ short Bl[128 * 64];
    gemm128_body<0>(A, Bt, bias, C, 512, blockIdx.x * 128, blockIdx.y * 128, Al, Bl);
}

// ---------------------------------------------------------------------------
// Flash attention v3: 128 q-rows/block (4 waves x 32 q), M-split=4, K/V
// double-buffered in LDS with register prefetch one tile ahead, attn_mat
// prefetched one tile ahead into regs, Q-LDS aliased as P-LDS after prologue.
// Single barrier per tile. No running max (|dots| bounded).
// This round: v_cvt_pk_bf16_f32 for P conversion (T12 primitive) + s_setprio
// around MFMA clusters (T5, attn-positive per m191).
// ---------------------------------------------------------------------------
__launch_bounds__(256)
__global__ void flash_attn(const unsigned short* __restrict__ qv,
                           const unsigned short* __restrict__ kb,
                           const float* __restrict__ attn_mat,
                           const float* __restrict__ dots_para,
                           const float* __restrict__ mat_para,
                           float* __restrict__ Opart,
                           float* __restrict__ lpart) {
    __shared__ short QP[4][32 * 64];   // Q (as flat 128x64) then per-wave P
    __shared__ short Ks[2][64 * 64];
    __shared__ short Vs[2][64 * 64];   // transposed [d][m], vswz layout

    const int tid = threadIdx.x, w = tid >> 6, lane = tid & 63;
    const int quad = lane >> 4, c16 = lane & 15;
    const int q0 = blockIdx.x * 128;
    const int bh = blockIdx.y;
    const int sp = blockIdx.z;
    const int b = bh >> 3, h = bh & 7;
    const int ms = sp * MSP;

    const float log2e = 1.4426950408889634f;
    const float mp = mat_para[0] * log2e;
    const float sdp = dots_para[0] * 0.125f * log2e;

    // ---- stage Q (128 x 64), read frags, then alias QP as P-scratch ----
    short* QPf = (short*)QP;
#pragma unroll
    for (int p = 0; p < 4; p++) {
        int id = p * 256 + tid;
        int r = id >> 3, c = id & 7;
        *(uint4*)&QPf[swz(r, c * 8)] =
            *(const uint4*)(qv + (size_t)(b * NB + q0 + r) * 1024 + h * 64 + c * 8);
    }
    __syncthreads();
    short8 qf[2][2];
#pragma unroll
    for (int at = 0; at < 2; at++)
#pragma unroll
        for (int kc = 0; kc < 2; kc++)
            qf[at][kc] = *(const short8*)&QPf[swz(w * 32 + at * 16 + c16, kc * 32 + quad * 8)];
    short* Pw = &QPf[w * 2048];  // wave-private 32x64 region (same rows Q frags came from)

    // ---- prefetch helpers ----
    const int sr = tid >> 3, sc = tid & 7;  // staging row/chunk for this thread (id & 511)
    uint4 kreg[2], vreg[2];
    auto loadKV = [&](int m) {
#pragma unroll
        for (int p = 0; p < 2; p++) {
            int r = p * 32 + sr;
            kreg[p] = *(const uint4*)(kb + (size_t)(b * MB + m + r) * 512 + h * 64 + sc * 8);
            vreg[p] = *(const uint4*)(qv + (size_t)(b * NB + m + r) * 1024 + 512 + h * 64 + sc * 8);
        }
    };
    auto storeKV = [&](int bufi) {
#pragma unroll
        for (int p = 0; p < 2; p++) {
            int r = p * 32 + sr;
            *(uint4*)&Ks[bufi][swz(r, sc * 8)] = kreg[p];
            uint4 d = vreg[p];
            Vs[bufi][vswz(sc * 8 + 0, r)] = (short)(d.x & 0xffff);
            Vs[bufi][vswz(sc * 8 + 1, r)] = (short)(d.x >> 16);
            Vs[bufi][vswz(sc * 8 + 2, r)] = (short)(d.y & 0xffff);
            Vs[bufi][vswz(sc * 8 + 3, r)] = (short)(d.y >> 16);
            Vs[bufi][vswz(sc * 8 + 4, r)] = (short)(d.z & 0xffff);
            Vs[bufi][vswz(sc * 8 + 5, r)] = (short)(d.z >> 16);
            Vs[bufi][vswz(sc * 8 + 6, r)] = (short)(d.w & 0xffff);
            Vs[bufi][vswz(sc * 8 + 7, r)] = (short)(d.w >> 16);
        }
    };
    const float* amp = attn_mat + ((size_t)bh * NB + q0 + w * 32 + quad * 4) * MB + c16;
    float amr[2][4][4];
    auto loadAM = [&](int m0_) {
#pragma unroll
        for (int at = 0; at < 2; at++)
#pragma unroll
            for (int r = 0; r < 4; r++)
#pragma unroll
                for (int t = 0; t < 4; t++)
                    amr[at][t][r] = amp[(size_t)(at * 16 + r) * MB + m0_ + t * 16];
    };

    // ---- prologue: tile0 staged to buf0; tile1 in regs; am(0) in regs ----
    loadKV(ms);
    storeKV(0);
    loadKV(ms + 64 < ms + MSP ? ms + 64 : ms);
    loadAM(ms);

    floatx4 O[2][4];
    float l[2][4];
#pragma unroll
    for (int at = 0; at < 2; at++)
#pragma unroll
        for (int i = 0; i < 4; i++) { O[at][i] = floatx4{0.f, 0.f, 0.f, 0.f}; l[at][i] = 0.f; }

    for (int it = 0; it < MSP / 64; it++) {
        const int m0 = ms + it * 64;
        const int buf = it & 1, nbuf = buf ^ 1;
        __syncthreads();                 // waves done reading buf^1; prefetches drained
        storeKV(nbuf);                   // stage tile it+1
        int mnn = m0 + 128; if (mnn >= ms + MSP) mnn = ms;
        loadKV(mnn);                     // issue global loads for tile it+2

        // S = Q K^T
        floatx4 S[2][4];
        __builtin_amdgcn_s_setprio(1);
#pragma unroll
        for (int t = 0; t < 4; t++) {
            short8 kf0 = *(const short8*)&Ks[buf][swz(t * 16 + c16, quad * 8)];
            short8 kf1 = *(const short8*)&Ks[buf][swz(t * 16 + c16, 32 + quad * 8)];
#pragma unroll
            for (int at = 0; at < 2; at++) {
                floatx4 s = floatx4{0.f, 0.f, 0.f, 0.f};
                s = __builtin_amdgcn_mfma_f32_16x16x32_bf16(qf[at][0], kf0, s, 0, 0, 0);
                s = __builtin_amdgcn_mfma_f32_16x16x32_bf16(qf[at][1], kf1, s, 0, 0, 0);
                S[at][t] = s;
            }
        }
        __builtin_amdgcn_s_setprio(0);

        // P = exp2(S*sdp + am*mp), row sums, packed bf16 cvt, store to wave-private LDS
#pragma unroll
        for (int at = 0; at < 2; at++)
#pragma unroll
            for (int t = 0; t < 4; t++) {
                float p0 = exp2f(fmaf(S[at][t][0], sdp, amr[at][t][0] * mp));
                float p1 = exp2f(fmaf(S[at][t][1], sdp, amr[at][t][1] * mp));
                float p2 = exp2f(fmaf(S[at][t][2], sdp, amr[at][t][2] * mp));
                float p3 = exp2f(fmaf(S[at][t][3], sdp, amr[at][t][3] * mp));
                l[at][0] += p0; l[at][1] += p1; l[at][2] += p2; l[at][3] += p3;
                unsigned int w01, w23;
                asm("v_cvt_pk_bf16_f32 %0, %1, %2" : "=v"(w01) : "v"(p0), "v"(p1));
                asm("v_cvt_pk_bf16_f32 %0, %1, %2" : "=v"(w23) : "v"(p2), "v"(p3));
                int br = at * 16 + quad * 4;
                Pw[swz(br + 0, t * 16 + c16)] = (short)(w01 & 0xffff);
                Pw[swz(br + 1, t * 16 + c16)] = (short)(w01 >> 16);
                Pw[swz(br + 2, t * 16 + c16)] = (short)(w23 & 0xffff);
                Pw[swz(br + 3, t * 16 + c16)] = (short)(w23 >> 16);
            }
        int mnx = m0 + 64; if (mnx >= ms + MSP) mnx = ms;
        loadAM(mnx);                     // prefetch am for tile it+1
        __threadfence_block();

        // O += P V
        short8 pf[2][2];
#pragma unroll
        for (int at = 0; at < 2; at++)
#pragma unroll
            for (int kc = 0; kc < 2; kc++)
                pf[at][kc] = *(const short8*)&Pw[swz(at * 16 + c16, kc * 32 + quad * 8)];
        __builtin_amdgcn_s_setprio(1);
#pragma unroll
        for (int dt = 0; dt < 4; dt++) {
            short8 vf0 = *(const short8*)&Vs[buf][vswz(dt * 16 + c16, quad * 8)];
            short8 vf1 = *(const short8*)&Vs[buf][vswz(dt * 16 + c16, 32 + quad * 8)];
#pragma unroll
            for (int at = 0; at < 2; at++) {
                O[at][dt] = __builtin_amdgcn_mfma_f32_16x16x32_bf16(pf[at][0], vf0, O[at][dt], 0, 0, 0);
                O[at][dt] = __builtin_amdgcn_mfma_f32_16x16x32_bf16(pf[at][1], vf1, O[at][dt], 0, 0, 0);
            }
        }
        __builtin_amdgcn_s_setprio(0);
    }

    // row sums across the 16 lanes of each quad; write partial l and O
#pragma unroll
    for (int at = 0; at < 2; at++) {
#pragma unroll
        for (int r = 0; r < 4; r++) {
            float s = l[at][r];
            s += __shfl_xor(s, 1);
            s += __shfl_xor(s, 2);
            s += __shfl_xor(s, 4);
            s += __shfl_xor(s, 8);
            l[at][r] = s;
        }
        if (c16 == 0) {
#pragma unroll
            for (int r = 0; r < 4; r++)
                lpart[(size_t)(sp * 16 + bh) * NB + q0 + w * 32 + at * 16 + quad * 4 + r] = l[at][r];
        }
#pragma unroll
        for (int dt = 0; dt < 4; dt++)
#pragma unroll
            for (int r = 0; r < 4; r++) {
                size_t row = (size_t)sp * 4096 + b * NB + q0 + w * 32 + at * 16 + quad * 4 + r;
                Opart[row * 512 + h * 64 + dt * 16 + c16] = O[at][dt][r];
            }
    }
}

// ---------------------------------------------------------------------------
// Combine 4 M-splits: ao = (sum O_s) / (sum l_s), bf16.
// ---------------------------------------------------------------------------
__launch_bounds__(256)
__global__ void combine_splits(const float* __restrict__ Opart, const float* __restrict__ lpart,
                               unsigned short* __restrict__ ao) {
    int idx = blockIdx.x * 256 + threadIdx.x;  // one float4-group; 4096 rows x 128 groups
    int row = idx >> 7;
    int col = (idx & 127) << 2;
    int b = row >> 11, n = row & 2047, h = col >> 6;
    float ls = 0.f;
    float4 o = {0.f, 0.f, 0.f, 0.f};
#pragma unroll
    for (int sp = 0; sp < SPLITS; sp++) {
        ls += lpart[(size_t)(sp * 16 + b * 8 + h) * NB + n];
        float4 os = *(const float4*)(Opart + ((size_t)sp * 4096 + row) * 512 + col);
        o.x += os.x; o.y += os.y; o.z += os.z; o.w += os.w;
    }
    float rinv = 1.0f / ls;
    uint2 pk;
    pk.x = (unsigned int)f2bf(o.x * rinv) | ((unsigned int)f2bf(o.y * rinv) << 16);
    pk.y = (unsigned int)f2bf(o.z * rinv) | ((unsigned int)f2bf(o.w * rinv) << 16);
    *(uint2*)(ao + (size_t)row * 512 + col) = pk;
}

extern "C" void kernel_launch(void* const* d_in, const int* in_sizes, int n_in,
                              void* d_out, int out_size, void* d_ws, size_t ws_size,
                              hipStream_t stream) {
    const float* x         = (const float*)d_in[0];
    const float* x1        = (const float*)d_in[1];
    const float* attn_mat  = (const float*)d_in[2];
    const float* dots_para = (const float*)d_in[3];
    const float* mat_para  = (const float*)d_in[4];
    const float* W_qv      = (const float*)d_in[5];
    const float* W_k       = (const float*)d_in[6];
    const float* W_out     = (const float*)d_in[7];
    const float* b_out     = (const float*)d_in[8];
    float* out = (float*)d_out;

    unsigned short* xb    = (unsigned short*)d_ws;                  // [4096,512]
    unsigned short* x1b   = xb    + (size_t)4096 * 512;
    unsigned short* qvbf  = x1b   + (size_t)4096 * 512;             // [4096,1024]
    unsigned short* kbf   = qvbf  + (size_t)4096 * 1024;            // [4096,512]
    unsigned short* aobf  = kbf   + (size_t)4096 * 512;             // [4096,512]
    unsigned short* Wqvt  = aobf  + (size_t)4096 * 512;             // [1024,512]
    unsigned short* Wkt   = Wqvt  + (size_t)1024 * 512;             // [512,512]
    unsigned short* Woutt = Wkt   + (size_t)512 * 512;              // [512,512]
    float*          Opart = (float*)(Woutt + (size_t)512 * 512);    // [4,4096,512]
    float*          lpart = Opart + (size_t)SPLITS * 4096 * 512;    // [4,16,2048]

    dim3 blk(256);
    prep<<<2304, blk, 0, stream>>>(x, x1, W_qv, W_k, W_out, xb, x1b, Wqvt, Wkt, Woutt);
    gemm_qvk<<<384, blk, 0, stream>>>(xb, x1b, Wqvt, Wkt, qvbf, kbf);
    flash_attn<<<dim3(16, 16, SPLITS), blk, 0, stream>>>(qvbf, kbf, attn_mat, dots_para, mat_para, Opart, lpart);
    combine_splits<<<2048, blk, 0, stream>>>(Opart, lpart, aobf);
    gemm_out<<<dim3(32, 4), blk, 0, stream>>>(aobf, Woutt, b_out, out);
}

// Round 2
// 432.789 us; speedup vs baseline: 1.0384x; 1.0150x over previous
//
#include <hip/hip_runtime.h>

#define NB 2048
#define MB 2048
#define SPLITS 4
#define MSP (MB / SPLITS)  // 512

typedef __attribute__((ext_vector_type(8))) short short8;
typedef __attribute__((ext_vector_type(4))) float floatx4;

__device__ __forceinline__ unsigned short f2bf(float f) {
    union { float f; unsigned int u; } v; v.f = f;
    unsigned int r = (v.u + 0x7FFFu + ((v.u >> 16) & 1u)) >> 16;
    return (unsigned short)r;
}

// XOR-swizzled LDS layout: 64 elems/row, 16B chunks swizzled by row low bits.
__device__ __forceinline__ int swz(int row, int k) {
    return (row << 6) + ((((k >> 3) ^ (row & 7))) << 3) + (k & 7);
}
// Variant for transposed-V (row = c*8+i pattern in staging).
__device__ __forceinline__ int vswz(int row, int k) {
    return (row << 6) + ((((k >> 3) ^ (row & 7) ^ ((row >> 3) & 7))) << 3) + (k & 7);
}

// async global -> LDS, 16B per lane. LDS dest must be wave-uniform + lane*16B
// (guaranteed here: dest index = p*256 + tid). Source is per-lane -> we XOR the
// source chunk index so that a linear LDS write + swz() read is conflict-free
// (rule 21: same involution on source and read side).
__device__ __forceinline__ void gload16(const unsigned short* g, short* l) {
    __builtin_amdgcn_global_load_lds(
        (const __attribute__((address_space(1))) void*)g,
        (__attribute__((address_space(3))) void*)l, 16, 0, 0);
}

// ---------------------------------------------------------------------------
// prep: fused  cvt(x), cvt(x1), transpose_cvt(W_qv), (W_k), (W_out)
// ---------------------------------------------------------------------------
__launch_bounds__(256)
__global__ void prep(const float* __restrict__ x, const float* __restrict__ x1,
                     const float* __restrict__ Wqv, const float* __restrict__ Wk,
                     const float* __restrict__ Wout,
                     unsigned short* __restrict__ xb, unsigned short* __restrict__ x1b,
                     unsigned short* __restrict__ Wqvt, unsigned short* __restrict__ Wkt,
                     unsigned short* __restrict__ Woutt) {
    __shared__ float t[64][65];
    const int bid = blockIdx.x, tid = threadIdx.x;
    if (bid < 2048) {
        const float* in = bid < 1024 ? x : x1;
        unsigned short* out = bid < 1024 ? xb : x1b;
        size_t off = ((size_t)(bid & 1023) * 256 + tid) * 8;
        float4 d0 = *(const float4*)(in + off);
        float4 d1 = *(const float4*)(in + off + 4);
        uint4 o;
        o.x = (unsigned int)f2bf(d0.x) | ((unsigned int)f2bf(d0.y) << 16);
        o.y = (unsigned int)f2bf(d0.z) | ((unsigned int)f2bf(d0.w) << 16);
        o.z = (unsigned int)f2bf(d1.x) | ((unsigned int)f2bf(d1.y) << 16);
        o.w = (unsigned int)f2bf(d1.z) | ((unsigned int)f2bf(d1.w) << 16);
        *(uint4*)(out + off) = o;
        return;
    }
    int tb = bid - 2048;
    const float* W; unsigned short* Wt; int N;
    if (tb < 128)      { W = Wqv;  Wt = Wqvt;  N = 1024; }
    else if (tb < 192) { tb -= 128; W = Wk;   Wt = Wkt;   N = 512; }
    else               { tb -= 192; W = Wout; Wt = Woutt; N = 512; }
    const int k0 = (tb & 7) * 64, n0 = (tb >> 3) * 64;
#pragma unroll
    for (int p = 0; p < 4; p++) {
        int idx = p * 256 + tid;
        int kr = idx >> 4, c4 = (idx & 15) << 2;
        float4 d = *(const float4*)(W + (size_t)(k0 + kr) * N + n0 + c4);
        t[kr][c4 + 0] = d.x; t[kr][c4 + 1] = d.y; t[kr][c4 + 2] = d.z; t[kr][c4 + 3] = d.w;
    }
    __syncthreads();
#pragma unroll
    for (int p = 0; p < 4; p++) {
        int idx = p * 256 + tid;
        int nr = idx >> 4, k4 = (idx & 15) << 2;
        uint2 o;
        o.x = (unsigned int)f2bf(t[k4 + 0][nr]) | ((unsigned int)f2bf(t[k4 + 1][nr]) << 16);
        o.y = (unsigned int)f2bf(t[k4 + 2][nr]) | ((unsigned int)f2bf(t[k4 + 3][nr]) << 16);
        *(uint2*)(Wt + (size_t)(n0 + nr) * 512 + k0 + k4) = o;
    }
}

// ---------------------------------------------------------------------------
// 128x64-tile bf16 GEMM, T3-minimal pipeline: double-buffered LDS, stage(next)
// issued before compute(cur), ONE __syncthreads per K-step (drains vmcnt).
// 4 waves in 2x2, each owns a 64x32 quadrant. Swizzled staging via
// pre-swizzled global source + swz() reads (free T2, 2-way max conflict).
// ---------------------------------------------------------------------------
template <int OUT_BF16>
__device__ __forceinline__ void gemm_body(const unsigned short* __restrict__ A,
                                          const unsigned short* __restrict__ Bt,
                                          const float* __restrict__ bias,
                                          void* __restrict__ Cp, int Nc, int m0, int n0,
                                          short* Al, short* Bl) {
    const int tid = threadIdx.x;
    const int w = tid >> 6, lane = tid & 63;
    const int quad = lane >> 4, c16 = lane & 15;
    const int wm = (w >> 1) * 64, wn = (w & 1) * 32;

    floatx4 acc[4][2];
#pragma unroll
    for (int i = 0; i < 4; i++)
#pragma unroll
        for (int j = 0; j < 2; j++) acc[i][j] = floatx4{0.f, 0.f, 0.f, 0.f};

    const unsigned short* Ap = A + (size_t)m0 * 512;
    const unsigned short* Bp = Bt + (size_t)n0 * 512;

    auto stage = [&](int bufi, int kk) {
#pragma unroll
        for (int p = 0; p < 4; p++) {
            int idx = p * 256 + tid;
            int row = idx >> 3, c = idx & 7;
            gload16(Ap + (size_t)row * 512 + kk + ((c ^ (row & 7)) << 3),
                    Al + bufi * 8192 + idx * 8);
        }
#pragma unroll
        for (int p = 0; p < 2; p++) {
            int idx = p * 256 + tid;
            int row = idx >> 3, c = idx & 7;
            gload16(Bp + (size_t)row * 512 + kk + ((c ^ (row & 7)) << 3),
                    Bl + bufi * 4096 + idx * 8);
        }
    };

    stage(0, 0);
    __syncthreads();                     // drains vmcnt(0): buf0 ready

    for (int ks = 0; ks < 8; ks++) {
        const int buf = ks & 1;
        if (ks < 7) stage(buf ^ 1, (ks + 1) * 64);   // overlaps compute below
#pragma unroll
        for (int kc = 0; kc < 2; kc++) {
            short8 af[4], bf[2];
#pragma unroll
            for (int mt = 0; mt < 4; mt++)
                af[mt] = *(const short8*)&Al[buf * 8192 + swz(wm + mt * 16 + c16, kc * 32 + quad * 8)];
#pragma unroll
            for (int nt = 0; nt < 2; nt++)
                bf[nt] = *(const short8*)&Bl[buf * 4096 + swz(wn + nt * 16 + c16, kc * 32 + quad * 8)];
#pragma unroll
            for (int mt = 0; mt < 4; mt++)
#pragma unroll
                for (int nt = 0; nt < 2; nt++)
                    acc[mt][nt] = __builtin_amdgcn_mfma_f32_16x16x32_bf16(af[mt], bf[nt], acc[mt][nt], 0, 0, 0);
        }
        __syncthreads();                 // drains stage(next); protects buf reuse
    }
#pragma unroll
    for (int mt = 0; mt < 4; mt++)
#pragma unroll
        for (int nt = 0; nt < 2; nt++)
#pragma unroll
            for (int r = 0; r < 4; r++) {
                int row = m0 + wm + mt * 16 + quad * 4 + r;
                int col = n0 + wn + nt * 16 + c16;
                float v = acc[mt][nt][r];
                if (OUT_BF16) {
                    ((unsigned short*)Cp)[(size_t)row * Nc + col] = f2bf(v);
                } else {
                    ((float*)Cp)[(size_t)row * Nc + col] = v + bias[col];
                }
            }
}

// Fused qv + k projection: blocks [0,512) -> qv (Nc=1024, 32x16 tiles),
// [512,768) -> k (Nc=512, 32x8 tiles). 768 blocks = 3/CU.
__launch_bounds__(256)
__global__ void gemm_qvk(const unsigned short* __restrict__ xb, const unsigned short* __restrict__ x1b,
                         const unsigned short* __restrict__ Wqvt, const unsigned short* __restrict__ Wkt,
                         unsigned short* __restrict__ qvbf, unsigned short* __restrict__ kbf) {
    __shared__ short Al[2 * 128 * 64];
    __shared__ short Bl[2 * 64 * 64];
    int bid = blockIdx.x;
    if (bid < 512) {
        gemm_body<1>(xb, Wqvt, nullptr, qvbf, 1024, (bid & 31) * 128, (bid >> 5) * 64, Al, Bl);
    } else {
        bid -= 512;
        gemm_body<1>(x1b, Wkt, nullptr, kbf, 512, (bid & 31) * 128, (bid >> 5) * 64, Al, Bl);
    }
}

__launch_bounds__(256)
__global__ void gemm_out(const unsigned short* __restrict__ A, const unsigned short* __restrict__ Bt,
                         const float* __restrict__ bias, float* __restrict__ C) {
    __shared__ short Al[2 * 128 * 64];
    __shared__ short Bl[2 * 64 * 64];
    gemm_body<0>(A, Bt, bias, C, 512, blockIdx.x * 128, blockIdx.y * 64, Al, Bl);
}

// ---------------------------------------------------------------------------
// Flash attention: 128 q-rows/block (4 waves x 32 q), M-split=4. K staged via
// global_load_lds (pre-swizzled source) one tile ahead; V reg-staged two ahead
// (needs elementwise transpose); attn_mat reg-prefetched one ahead; Q staged
// via global_load_lds then aliased as P-LDS. Single barrier per tile.
// ---------------------------------------------------------------------------
__launch_bounds__(256)
__global__ void flash_attn(const unsigned short* __restrict__ qv,
                           const unsigned short* __restrict__ kb,
                           const float* __restrict__ attn_mat,
                           const float* __restrict__ dots_para,
                           const float* __restrict__ mat_para,
                           float* __restrict__ Opart,
                           float* __restrict__ lpart) {
    __shared__ short QP[4][32 * 64];   // Q (as flat 128x64) then per-wave P
    __shared__ short Ks[2][64 * 64];
    __shared__ short Vs[2][64 * 64];   // transposed [d][m], vswz layout

    const int tid = threadIdx.x, w = tid >> 6, lane = tid & 63;
    const int quad = lane >> 4, c16 = lane & 15;
    const int q0 = blockIdx.x * 128;
    const int bh = blockIdx.y;
    const int sp = blockIdx.z;
    const int b = bh >> 3, h = bh & 7;
    const int ms = sp * MSP;

    const float log2e = 1.4426950408889634f;
    const float mp = mat_para[0] * log2e;
    const float sdp = dots_para[0] * 0.125f * log2e;

    short* QPf = (short*)QP;
    const int sr = tid >> 3, sc = tid & 7;  // V staging row/chunk

    // ---- Q stage via global_load_lds (pre-swizzled source) ----
#pragma unroll
    for (int p = 0; p < 4; p++) {
        int idx = p * 256 + tid;
        int r = idx >> 3, c = idx & 7;
        gload16(qv + (size_t)(b * NB + q0 + r) * 1024 + h * 64 + ((c ^ (r & 7)) << 3),
                QPf + idx * 8);
    }

    // ---- K stage via global_load_lds (pre-swizzled source) ----
    auto gloadK = [&](int bufi, int m) {
#pragma unroll
        for (int p = 0; p < 2; p++) {
            int idx = p * 256 + tid;
            int row = idx >> 3, c = idx & 7;
            gload16(kb + (size_t)(b * MB + m + row) * 512 + h * 64 + ((c ^ (row & 7)) << 3),
                    &Ks[bufi][idx * 8]);
        }
    };

    uint4 vreg[2];
    auto loadV = [&](int m) {
#pragma unroll
        for (int p = 0; p < 2; p++) {
            int r = p * 32 + sr;
            vreg[p] = *(const uint4*)(qv + (size_t)(b * NB + m + r) * 1024 + 512 + h * 64 + sc * 8);
        }
    };
    auto storeV = [&](int bufi) {
#pragma unroll
        for (int p = 0; p < 2; p++) {
            int r = p * 32 + sr;
            uint4 d = vreg[p];
            Vs[bufi][vswz(sc * 8 + 0, r)] = (short)(d.x & 0xffff);
            Vs[bufi][vswz(sc * 8 + 1, r)] = (short)(d.x >> 16);
            Vs[bufi][vswz(sc * 8 + 2, r)] = (short)(d.y & 0xffff);
            Vs[bufi][vswz(sc * 8 + 3, r)] = (short)(d.y >> 16);
            Vs[bufi][vswz(sc * 8 + 4, r)] = (short)(d.z & 0xffff);
            Vs[bufi][vswz(sc * 8 + 5, r)] = (short)(d.z >> 16);
            Vs[bufi][vswz(sc * 8 + 6, r)] = (short)(d.w & 0xffff);
            Vs[bufi][vswz(sc * 8 + 7, r)] = (short)(d.w >> 16);
        }
    };
    const float* amp = attn_mat + ((size_t)bh * NB + q0 + w * 32 + quad * 4) * MB + c16;
    float amr[2][4][4];
    auto loadAM = [&](int m0_) {
#pragma unroll
        for (int at = 0; at < 2; at++)
#pragma unroll
            for (int r = 0; r < 4; r++)
#pragma unroll
                for (int t = 0; t < 4; t++)
                    amr[at][t][r] = amp[(size_t)(at * 16 + r) * MB + m0_ + t * 16];
    };

    // ---- prologue ----
    gloadK(0, ms);
    loadV(ms);
    loadAM(ms);
    __syncthreads();                 // Q + K0 in LDS (vmcnt drained)
    short8 qf[2][2];
#pragma unroll
    for (int at = 0; at < 2; at++)
#pragma unroll
        for (int kc = 0; kc < 2; kc++)
            qf[at][kc] = *(const short8*)&QPf[swz(w * 32 + at * 16 + c16, kc * 32 + quad * 8)];
    short* Pw = &QPf[w * 2048];      // wave-private 32x64 region
    storeV(0);                       // V tile0 -> Vs[0]
    loadV(ms + 64);                  // V tile1 -> regs

    floatx4 O[2][4];
    float l[2][4];
#pragma unroll
    for (int at = 0; at < 2; at++)
#pragma unroll
        for (int i = 0; i < 4; i++) { O[at][i] = floatx4{0.f, 0.f, 0.f, 0.f}; l[at][i] = 0.f; }

    for (int it = 0; it < MSP / 64; it++) {
        const int m0 = ms + it * 64;
        const int buf = it & 1, nbuf = buf ^ 1;
        __syncthreads();             // buf K/V ready; all waves done with nbuf
        int mn1 = m0 + 64;  if (mn1 >= ms + MSP) mn1 = ms;
        int mn2 = m0 + 128; if (mn2 >= ms + MSP) mn2 = ms;
        gloadK(nbuf, mn1);           // K tile it+1 (drains at next barrier)
        storeV(nbuf);                // V tile it+1 from regs
        loadV(mn2);                  // V tile it+2 -> regs

        // S = Q K^T
        floatx4 S[2][4];
        __builtin_amdgcn_s_setprio(1);
#pragma unroll
        for (int t = 0; t < 4; t++) {
            short8 kf0 = *(const short8*)&Ks[buf][swz(t * 16 + c16, quad * 8)];
            short8 kf1 = *(const short8*)&Ks[buf][swz(t * 16 + c16, 32 + quad * 8)];
#pragma unroll
            for (int at = 0; at < 2; at++) {
                floatx4 s = floatx4{0.f, 0.f, 0.f, 0.f};
                s = __builtin_amdgcn_mfma_f32_16x16x32_bf16(qf[at][0], kf0, s, 0, 0, 0);
                s = __builtin_amdgcn_mfma_f32_16x16x32_bf16(qf[at][1], kf1, s, 0, 0, 0);
                S[at][t] = s;
            }
        }
        __builtin_amdgcn_s_setprio(0);

        // P = exp2(S*sdp + am*mp), row sums, packed bf16 cvt, store to wave LDS
#pragma unroll
        for (int at = 0; at < 2; at++)
#pragma unroll
            for (int t = 0; t < 4; t++) {
                float p0 = exp2f(fmaf(S[at][t][0], sdp, amr[at][t][0] * mp));
                float p1 = exp2f(fmaf(S[at][t][1], sdp, amr[at][t][1] * mp));
                float p2 = exp2f(fmaf(S[at][t][2], sdp, amr[at][t][2] * mp));
                float p3 = exp2f(fmaf(S[at][t][3], sdp, amr[at][t][3] * mp));
                l[at][0] += p0; l[at][1] += p1; l[at][2] += p2; l[at][3] += p3;
                unsigned int w01, w23;
                asm("v_cvt_pk_bf16_f32 %0, %1, %2" : "=v"(w01) : "v"(p0), "v"(p1));
                asm("v_cvt_pk_bf16_f32 %0, %1, %2" : "=v"(w23) : "v"(p2), "v"(p3));
                int br = at * 16 + quad * 4;
                Pw[swz(br + 0, t * 16 + c16)] = (short)(w01 & 0xffff);
                Pw[swz(br + 1, t * 16 + c16)] = (short)(w01 >> 16);
                Pw[swz(br + 2, t * 16 + c16)] = (short)(w23 & 0xffff);
                Pw[swz(br + 3, t * 16 + c16)] = (short)(w23 >> 16);
            }
        loadAM(mn1);                 // prefetch am for tile it+1
        __threadfence_block();

        // O += P V
        short8 pf[2][2];
#pragma unroll
        for (int at = 0; at < 2; at++)
#pragma unroll
            for (int kc = 0; kc < 2; kc++)
                pf[at][kc] = *(const short8*)&Pw[swz(at * 16 + c16, kc * 32 + quad * 8)];
        __builtin_amdgcn_s_setprio(1);
#pragma unroll
        for (int dt = 0; dt < 4; dt++) {
            short8 vf0 = *(const short8*)&Vs[buf][vswz(dt * 16 + c16, quad * 8)];
            short8 vf1 = *(const short8*)&Vs[buf][vswz(dt * 16 + c16, 32 + quad * 8)];
#pragma unroll
            for (int at = 0; at < 2; at++) {
                O[at][dt] = __builtin_amdgcn_mfma_f32_16x16x32_bf16(pf[at][0], vf0, O[at][dt], 0, 0, 0);
                O[at][dt] = __builtin_amdgcn_mfma_f32_16x16x32_bf16(pf[at][1], vf1, O[at][dt], 0, 0, 0);
            }
        }
        __builtin_amdgcn_s_setprio(0);
    }

    // row sums across the 16 lanes of each quad; write partial l and O
#pragma unroll
    for (int at = 0; at < 2; at++) {
#pragma unroll
        for (int r = 0; r < 4; r++) {
            float s = l[at][r];
            s += __shfl_xor(s, 1);
            s += __shfl_xor(s, 2);
            s += __shfl_xor(s, 4);
            s += __shfl_xor(s, 8);
            l[at][r] = s;
        }
        if (c16 == 0) {
#pragma unroll
            for (int r = 0; r < 4; r++)
                lpart[(size_t)(sp * 16 + bh) * NB + q0 + w * 32 + at * 16 + quad * 4 + r] = l[at][r];
        }
#pragma unroll
        for (int dt = 0; dt < 4; dt++)
#pragma unroll
            for (int r = 0; r < 4; r++) {
                size_t row = (size_t)sp * 4096 + b * NB + q0 + w * 32 + at * 16 + quad * 4 + r;
                Opart[row * 512 + h * 64 + dt * 16 + c16] = O[at][dt][r];
            }
    }
}

// ---------------------------------------------------------------------------
// Combine 4 M-splits: ao = (sum O_s) / (sum l_s), bf16.
// ---------------------------------------------------------------------------
__launch_bounds__(256)
__global__ void combine_splits(const float* __restrict__ Opart, const float* __restrict__ lpart,
                               unsigned short* __restrict__ ao) {
    int idx = blockIdx.x * 256 + threadIdx.x;  // one float4-group; 4096 rows x 128 groups
    int row = idx >> 7;
    int col = (idx & 127) << 2;
    int b = row >> 11, n = row & 2047, h = col >> 6;
    float ls = 0.f;
    float4 o = {0.f, 0.f, 0.f, 0.f};
#pragma unroll
    for (int sp = 0; sp < SPLITS; sp++) {
        ls += lpart[(size_t)(sp * 16 + b * 8 + h) * NB + n];
        float4 os = *(const float4*)(Opart + ((size_t)sp * 4096 + row) * 512 + col);
        o.x += os.x; o.y += os.y; o.z += os.z; o.w += os.w;
    }
    float rinv = 1.0f / ls;
    uint2 pk;
    pk.x = (unsigned int)f2bf(o.x * rinv) | ((unsigned int)f2bf(o.y * rinv) << 16);
    pk.y = (unsigned int)f2bf(o.z * rinv) | ((unsigned int)f2bf(o.w * rinv) << 16);
    *(uint2*)(ao + (size_t)row * 512 + col) = pk;
}

extern "C" void kernel_launch(void* const* d_in, const int* in_sizes, int n_in,
                              void* d_out, int out_size, void* d_ws, size_t ws_size,
                              hipStream_t stream) {
    const float* x         = (const float*)d_in[0];
    const float* x1        = (const float*)d_in[1];
    const float* attn_mat  = (const float*)d_in[2];
    const float* dots_para = (const float*)d_in[3];
    const float* mat_para  = (const float*)d_in[4];
    const float* W_qv      = (const float*)d_in[5];
    const float* W_k       = (const float*)d_in[6];
    const float* W_out     = (const float*)d_in[7];
    const float* b_out     = (const float*)d_in[8];
    float* out = (float*)d_out;

    unsigned short* xb    = (unsigned short*)d_ws;                  // [4096,512]
    unsigned short* x1b   = xb    + (size_t)4096 * 512;
    unsigned short* qvbf  = x1b   + (size_t)4096 * 512;             // [4096,1024]
    unsigned short* kbf   = qvbf  + (size_t)4096 * 1024;            // [4096,512]
    unsigned short* aobf  = kbf   + (size_t)4096 * 512;             // [4096,512]
    unsigned short* Wqvt  = aobf  + (size_t)4096 * 512;             // [1024,512]
    unsigned short* Wkt   = Wqvt  + (size_t)1024 * 512;             // [512,512]
    unsigned short* Woutt = Wkt   + (size_t)512 * 512;              // [512,512]
    float*          Opart = (float*)(Woutt + (size_t)512 * 512);    // [4,4096,512]
    float*          lpart = Opart + (size_t)SPLITS * 4096 * 512;    // [4,16,2048]

    dim3 blk(256);
    prep<<<2304, blk, 0, stream>>>(x, x1, W_qv, W_k, W_out, xb, x1b, Wqvt, Wkt, Woutt);
    gemm_qvk<<<768, blk, 0, stream>>>(xb, x1b, Wqvt, Wkt, qvbf, kbf);
    flash_attn<<<dim3(16, 16, SPLITS), blk, 0, stream>>>(qvbf, kbf, attn_mat, dots_para, mat_para, Opart, lpart);
    combine_splits<<<2048, blk, 0, stream>>>(Opart, lpart, aobf);
    gemm_out<<<dim3(32, 8), blk, 0, stream>>>(aobf, Woutt, b_out, out);
}